// Round 8
// baseline (365.832 us; speedup 1.0000x reference)
//
#include <hip/hip_runtime.h>
#include <hip/hip_fp16.h>

#define T_STEPS 256
#define OBS 512      // obs dim = number of independent per-row LSTMs
#define ACT 32
#define HID 1024     // output rows (hidden_dim)
#define PED 128      // pos_em_dim = LSTM hidden size
#define MSG 128      // msg_dim
#define GATES 512    // 4*PED
#define HSTR 136     // h_s row stride in halfs
#define L1 1.4426950408889634f
#define L2C 2.8853900817779268f
// scale folded into q~ and cb: tanh(S/sqrt(128)) = 1 - 2/(exp2(QSCALE*S)+1)
#define QSCALE 0.2550348805576823f   // 2*log2(e)/sqrt(128)

typedef _Float16 half8  __attribute__((ext_vector_type(8)));
typedef float    floatx4 __attribute__((ext_vector_type(4)));

__device__ __forceinline__ float fast_exp2(float x) { return __builtin_amdgcn_exp2f(x); }
__device__ __forceinline__ float fast_rcp(float x)  { return __builtin_amdgcn_rcpf(x); }
__device__ __forceinline__ float tanh_f(float x) {
    return fmaf(-2.0f, fast_rcp(fast_exp2(2.8853900817779268f * x) + 1.0f), 1.0f);
}

// ---------------------------------------------------------------------------
// Kernel 1: xnorm[t,n]; apre in [t][p][g] layout:
//   apre_p[t*512 + p*4 + g] = b_ih[j]+b_hh[j]+act[t]·W_ih[j,1:],  j = 128g+p
// ---------------------------------------------------------------------------
__global__ void k_pre(const float* __restrict__ obs, const float* __restrict__ act,
                      const float* __restrict__ shift, const float* __restrict__ scale,
                      const float* __restrict__ W_ih, const float* __restrict__ b_ih,
                      const float* __restrict__ b_hh,
                      float* __restrict__ xnorm, float* __restrict__ apre_p) {
    int t = blockIdx.x;
    int tid = threadIdx.x;
    __shared__ float a_s[ACT];
    if (tid < ACT) a_s[tid] = act[t * ACT + tid];
    __syncthreads();
    for (int n = tid; n < OBS; n += 256) {
        xnorm[t * OBS + n] = (obs[t * OBS + n] - shift[n]) / (scale[n] + 1e-8f);
    }
    for (int j = tid; j < GATES; j += 256) {
        float acc = b_ih[j] + b_hh[j];
        const float* wr = W_ih + j * 33 + 1;
#pragma unroll
        for (int u = 0; u < ACT; ++u) acc = fmaf(a_s[u], wr[u], acc);
        int g = j >> 7, p = j & 127;
        apre_p[t * GATES + p * 4 + g] = acc;
    }
}

// ---------------------------------------------------------------------------
// Kernel 2: q~[m] = QSCALE * Wk^T (Wq pe_m + bq)  (fp16), cb[m] = QSCALE * q·bk
// ---------------------------------------------------------------------------
__global__ void k_qproj(const float* __restrict__ pe, const float* __restrict__ Wq,
                        const float* __restrict__ bq, const float* __restrict__ Wk,
                        const float* __restrict__ bk,
                        _Float16* __restrict__ qh, float* __restrict__ cb) {
    int m = blockIdx.x;
    int d = threadIdx.x;  // 0..127
    __shared__ float pe_s[PED];
    __shared__ float q_s[PED];
    __shared__ float red_s[2];
    pe_s[d] = pe[m * PED + d];
    __syncthreads();
    const float* wr = Wq + d * PED;
    float a = bq[d];
#pragma unroll 8
    for (int p = 0; p < PED; ++p) a = fmaf(pe_s[p], wr[p], a);
    q_s[d] = a;
    float pb = a * bk[d];
#pragma unroll
    for (int off = 32; off; off >>= 1) pb += __shfl_xor(pb, off, 64);
    if ((d & 63) == 0) red_s[d >> 6] = pb;
    __syncthreads();
    float acc = 0.f;
#pragma unroll 8
    for (int p = 0; p < PED; ++p) acc = fmaf(q_s[p], Wk[p * PED + d], acc);
    qh[m * PED + d] = (_Float16)(acc * QSCALE);
    if (d == 0) cb[m] = (red_s[0] + red_s[1]) * QSCALE;
}

// ---------------------------------------------------------------------------
// Kernel 3: LSTM scan via MFMA. 128 blocks x 512 threads (8 waves = 2/SIMD),
// 4 obs-rows/block, obs-row j stored at A-row 4j. Then C[row=4*quad][col=l15]
// puts exactly ONE cell per lane in acc[g][0]: no shuffles, no gate exchange.
// apre is folded into the MFMA accumulator init. Batched-rcp nonlinearities.
// ---------------------------------------------------------------------------
__global__ __launch_bounds__(512, 1)
void k_lstm(const float* __restrict__ xnorm, const float* __restrict__ apre_p,
            const float* __restrict__ W_ih, const float* __restrict__ W_hh,
            _Float16* __restrict__ H16) {
    const int tid = threadIdx.x;
    const int lane = tid & 63, wv = tid >> 6;     // 8 waves
    const int l15 = lane & 15, quad = lane >> 4;
    const int n0 = blockIdx.x * 4;
    const int p = 16 * wv + l15;                  // gate/h unit this lane owns

    // ---- stationary B-fragments: B[n=col][k] = W_hh[col][k], col = 128g+p
    half8 bfr[4][4];
    float wih0[4];
#pragma unroll
    for (int g = 0; g < 4; ++g) {
        const int col = 128 * g + p;
        const float* wrow = W_hh + (size_t)col * PED;
#pragma unroll
        for (int c = 0; c < 4; ++c) {
            const int k0 = c * 32 + quad * 8;
            float4 f0 = *(const float4*)(wrow + k0);
            float4 f1 = *(const float4*)(wrow + k0 + 4);
            bfr[g][c] = (half8){(_Float16)f0.x, (_Float16)f0.y, (_Float16)f0.z, (_Float16)f0.w,
                                (_Float16)f1.x, (_Float16)f1.y, (_Float16)f1.z, (_Float16)f1.w};
        }
        wih0[g] = W_ih[(size_t)col * 33];
    }

    __shared__ _Float16 h_s[2][16 * HSTR];        // A-rows 4j hold h, rest zero
    __shared__ float x_s[T_STEPS * 4];            // 4 KB

    for (int idx = tid; idx < T_STEPS * 4; idx += 512)
        x_s[idx] = xnorm[(idx >> 2) * OBS + n0 + (idx & 3)];
    for (int idx = tid; idx < 2 * 16 * HSTR; idx += 512)
        ((_Float16*)h_s)[idx] = (_Float16)0.f;

    float c0 = 0.f;
    const float* apl = apre_p + p * 4;
    float4 ap = *(const float4*)(apl);            // (gi,gf,gg,go) pre-adds for t=0
    __syncthreads();

    _Float16* Hg = H16 + (size_t)(n0 + quad) * MSG + p;
    int buf = 0;
    for (int t = 0; t < T_STEPS; ++t) {
        // ---- A-fragments: A[m=l15][k] from h_s (b128, conflict-free)
        half8 af[4];
        const _Float16* hb = h_s[buf] + l15 * HSTR + quad * 8;
#pragma unroll
        for (int c = 0; c < 4; ++c) af[c] = *(const half8*)(hb + c * 32);

        // ---- gates via MFMA, apre folded into acc init
        floatx4 acc[4];
        acc[0] = (floatx4){ap.x, ap.x, ap.x, ap.x};
        acc[1] = (floatx4){ap.y, ap.y, ap.y, ap.y};
        acc[2] = (floatx4){ap.z, ap.z, ap.z, ap.z};
        acc[3] = (floatx4){ap.w, ap.w, ap.w, ap.w};
#pragma unroll
        for (int g = 0; g < 4; ++g)
#pragma unroll
            for (int c = 0; c < 4; ++c)
                acc[g] = __builtin_amdgcn_mfma_f32_16x16x32_f16(
                    af[c], bfr[g][c], acc[g], 0, 0, 0);

        // ---- prefetch apre for t+1 (off critical path)
        const int tn = (t + 1 < T_STEPS) ? t + 1 : t;
        float4 ap_n = *(const float4*)(apl + tn * GATES);

        // ---- this lane's single cell: obs-row quad, unit p (C row 4*quad)
        const float x = x_s[t * 4 + quad];
        float gi = fmaf(x, wih0[0], acc[0][0]);
        float gf = fmaf(x, wih0[1], acc[1][0]);
        float gg = fmaf(x, wih0[2], acc[2][0]);
        float go = fmaf(x, wih0[3], acc[3][0]);

        // batched-rcp: 3 denominators, 1 rcp
        float Di = 1.f + fast_exp2(fminf(-L1 * gi, 20.f));
        float Df = 1.f + fast_exp2(fminf(-L1 * gf, 20.f));
        float Dg = 1.f + fast_exp2(fminf(L2C * gg, 20.f));
        float DfDg = Df * Dg, DiDg = Di * Dg, DiDf = Di * Df;
        float r3 = fast_rcp(Di * DfDg);
        float iDi = r3 * DfDg, iDf = r3 * DiDg, iDg = r3 * DiDf;
        float cn = fmaf(iDf, c0, iDi * fmaf(-2.f, iDg, 1.f));
        c0 = cn;
        float Do = 1.f + fast_exp2(fminf(-L1 * go, 20.f));
        float Dc = 1.f + fast_exp2(fminf(L2C * cn, 20.f));
        float r2 = fast_rcp(Do * Dc);
        float iDo = r2 * Dc, iDc = r2 * Do;
        _Float16 hq = (_Float16)(iDo * fmaf(-2.f, iDc, 1.f));

        // ---- write h to next LDS buffer (A-row 4*quad) + global H16
        h_s[buf ^ 1][(4 * quad) * HSTR + p] = hq;
        Hg[0] = hq;
        Hg += OBS * MSG;

        ap = ap_n;
        buf ^= 1;
        __syncthreads();
    }
}

// ---------------------------------------------------------------------------
// Kernel 4: attention via fp16 MFMA, LDS-free and barrier-free.
//   S = q~·h + cb (cb in acc init); w = 1-2/(exp2(S)+1); out = tanh(sum w*s)
// grid: T*8 blocks x 256 threads, 2 m-tiles/wave; B-frags read straight from
// L2-resident H16 (b128), next n-tile software-prefetched during epilogue.
// ---------------------------------------------------------------------------
__global__ __launch_bounds__(256, 4)
void k_attn(const _Float16* __restrict__ qh, const float* __restrict__ cb,
            const _Float16* __restrict__ H16, const float* __restrict__ xnorm,
            float* __restrict__ outp) {
    const int t = blockIdx.x >> 3;
    const int mq = blockIdx.x & 7;
    const int tid = threadIdx.x;
    const int lane = tid & 63, wave = tid >> 6;
    const int l15 = lane & 15, quad = lane >> 4;
    const int m0 = mq * 128 + wave * 32;

    half8 afrag[2][4];
    floatx4 cbv[2];
#pragma unroll
    for (int mt = 0; mt < 2; ++mt) {
        const half8* qrow = (const half8*)(qh + (size_t)(m0 + mt * 16 + l15) * PED);
#pragma unroll
        for (int c = 0; c < 4; ++c) afrag[mt][c] = qrow[c * 4 + quad];
        cbv[mt] = *(const floatx4*)(cb + m0 + mt * 16 + quad * 4);
    }

    float outacc[8];
#pragma unroll
    for (int i = 0; i < 8; ++i) outacc[i] = 0.f;

    const _Float16* Hb = H16 + (size_t)t * (OBS * MSG) + (size_t)l15 * MSG + quad * 8;
    const float* xb = xnorm + t * OBS + l15;

    half8 bf[4];
    float sv;
#pragma unroll
    for (int c = 0; c < 4; ++c) bf[c] = *(const half8*)(Hb + c * 32);
    sv = xb[0];

    for (int nt = 0; nt < 32; ++nt) {
        half8 bfn[4];
        float svn = 0.f;
        if (nt < 31) {
            const _Float16* Hn = Hb + (nt + 1) * (16 * MSG);
#pragma unroll
            for (int c = 0; c < 4; ++c) bfn[c] = *(const half8*)(Hn + c * 32);
            svn = xb[(nt + 1) * 16];
        }

        floatx4 acc[2];
#pragma unroll
        for (int mt = 0; mt < 2; ++mt) {
            acc[mt] = cbv[mt];
#pragma unroll
            for (int c = 0; c < 4; ++c)
                acc[mt] = __builtin_amdgcn_mfma_f32_16x16x32_f16(
                    afrag[mt][c], bf[c], acc[mt], 0, 0, 0);
        }

#pragma unroll
        for (int mt = 0; mt < 2; ++mt) {
            float E0 = fast_exp2(fminf(acc[mt][0], 20.f));
            float E1 = fast_exp2(fminf(acc[mt][1], 20.f));
            float E2 = fast_exp2(fminf(acc[mt][2], 20.f));
            float E3 = fast_exp2(fminf(acc[mt][3], 20.f));
            float D0 = 1.f + E0, D1 = 1.f + E1, D2 = 1.f + E2, D3 = 1.f + E3;
            float m01 = D0 * D1, m23 = D2 * D3;
            float rp = fast_rcp(m01 * m23);
            float rA = rp * m23, rB = rp * m01;
            float i0 = rA * D1, i1 = rA * D0, i2 = rB * D3, i3 = rB * D2;
            outacc[mt * 4 + 0] = fmaf(fmaf(-2.f, i0, 1.f), sv, outacc[mt * 4 + 0]);
            outacc[mt * 4 + 1] = fmaf(fmaf(-2.f, i1, 1.f), sv, outacc[mt * 4 + 1]);
            outacc[mt * 4 + 2] = fmaf(fmaf(-2.f, i2, 1.f), sv, outacc[mt * 4 + 2]);
            outacc[mt * 4 + 3] = fmaf(fmaf(-2.f, i3, 1.f), sv, outacc[mt * 4 + 3]);
        }

#pragma unroll
        for (int c = 0; c < 4; ++c) bf[c] = bfn[c];
        sv = svn;
    }

#pragma unroll
    for (int i = 0; i < 8; ++i) {
        float v = outacc[i];
        v += __shfl_xor(v, 1, 16);
        v += __shfl_xor(v, 2, 16);
        v += __shfl_xor(v, 4, 16);
        v += __shfl_xor(v, 8, 16);
        outacc[i] = v;
    }
    if (l15 == 0) {
        const int mbase = m0 + quad * 4;
#pragma unroll
        for (int mt = 0; mt < 2; ++mt)
#pragma unroll
            for (int r = 0; r < 4; ++r)
                outp[(size_t)t * HID + mbase + mt * 16 + r] = tanh_f(outacc[mt * 4 + r]);
    }
}

// ---------------------------------------------------------------------------
extern "C" void kernel_launch(void* const* d_in, const int* in_sizes, int n_in,
                              void* d_out, int out_size, void* d_ws, size_t ws_size,
                              hipStream_t stream) {
    const float* obs      = (const float*)d_in[0];   // (256,512)
    const float* prev_act = (const float*)d_in[1];   // (256,32)
    const float* in_shift = (const float*)d_in[2];   // (512,)
    const float* in_scale = (const float*)d_in[3];   // (512,)
    const float* pos_emb  = (const float*)d_in[4];   // (1024,128)
    const float* W_ih     = (const float*)d_in[5];   // (512,33)
    const float* b_ih     = (const float*)d_in[6];   // (512,)
    const float* W_hh     = (const float*)d_in[7];   // (512,128)
    const float* b_hh     = (const float*)d_in[8];   // (512,)
    const float* Wq       = (const float*)d_in[9];   // (128,128)
    const float* bq       = (const float*)d_in[10];  // (128,)
    const float* Wk       = (const float*)d_in[11];  // (128,128)
    const float* bk       = (const float*)d_in[12];  // (128,)
    float* outp = (float*)d_out;                     // (256,1024)

    // workspace layout (float offsets):
    //   xnorm:  0        (131072 f)
    //   apre_p: 131072   (131072 f)
    //   qh:     262144   (131072 halfs = 65536 f)
    //   cb:     327680   (1024 f)
    //   H16:    328704   (16777216 halfs)
    float* ws = (float*)d_ws;
    float* xnorm  = ws;
    float* apre_p = ws + 131072;
    _Float16* qh  = (_Float16*)(ws + 262144);
    float* cbuf   = ws + 327680;
    _Float16* H16 = (_Float16*)(ws + 328704);

    k_pre<<<T_STEPS, 256, 0, stream>>>(obs, prev_act, in_shift, in_scale,
                                       W_ih, b_ih, b_hh, xnorm, apre_p);
    k_qproj<<<HID, 128, 0, stream>>>(pos_emb, Wq, bq, Wk, bk, qh, cbuf);
    k_lstm<<<128, 512, 0, stream>>>(xnorm, apre_p, W_ih, W_hh, H16);
    k_attn<<<T_STEPS * 8, 256, 0, stream>>>(qh, cbuf, H16, xnorm, outp);
}

// Round 9
// 300.607 us; speedup vs baseline: 1.2170x; 1.2170x over previous
//
#include <hip/hip_runtime.h>
#include <hip/hip_fp16.h>

#define T_STEPS 256
#define OBS 512      // obs dim = number of independent per-row LSTMs
#define ACT 32
#define HID 1024     // output rows (hidden_dim)
#define PED 128      // pos_em_dim = LSTM hidden size
#define MSG 128      // msg_dim
#define GATES 512    // 4*PED
#define HSTR 136     // h_s row stride in halfs
#define KSTR 17      // kbuf row stride in half8 units (272B)
#define L1 1.4426950408889634f
#define L2C 2.8853900817779268f
// scale folded into q~ and cb: tanh(S/sqrt(128)) = 1 - 2/(exp2(QSCALE*S)+1)
#define QSCALE 0.2550348805576823f   // 2*log2(e)/sqrt(128)

typedef _Float16 half8  __attribute__((ext_vector_type(8)));
typedef float    floatx4 __attribute__((ext_vector_type(4)));

__device__ __forceinline__ float fast_exp2(float x) { return __builtin_amdgcn_exp2f(x); }
__device__ __forceinline__ float fast_rcp(float x)  { return __builtin_amdgcn_rcpf(x); }
__device__ __forceinline__ float tanh_f(float x) {
    return fmaf(-2.0f, fast_rcp(fast_exp2(2.8853900817779268f * x) + 1.0f), 1.0f);
}

// ---------------------------------------------------------------------------
// Kernel 1: xnorm[t,n]; apre in [t][p][g] layout:
//   apre_p[t*512 + p*4 + g] = b_ih[j]+b_hh[j]+act[t]·W_ih[j,1:],  j = 128g+p
// ---------------------------------------------------------------------------
__global__ void k_pre(const float* __restrict__ obs, const float* __restrict__ act,
                      const float* __restrict__ shift, const float* __restrict__ scale,
                      const float* __restrict__ W_ih, const float* __restrict__ b_ih,
                      const float* __restrict__ b_hh,
                      float* __restrict__ xnorm, float* __restrict__ apre_p) {
    int t = blockIdx.x;
    int tid = threadIdx.x;
    __shared__ float a_s[ACT];
    if (tid < ACT) a_s[tid] = act[t * ACT + tid];
    __syncthreads();
    for (int n = tid; n < OBS; n += 256) {
        xnorm[t * OBS + n] = (obs[t * OBS + n] - shift[n]) / (scale[n] + 1e-8f);
    }
    for (int j = tid; j < GATES; j += 256) {
        float acc = b_ih[j] + b_hh[j];
        const float* wr = W_ih + j * 33 + 1;
#pragma unroll
        for (int u = 0; u < ACT; ++u) acc = fmaf(a_s[u], wr[u], acc);
        int g = j >> 7, p = j & 127;
        apre_p[t * GATES + p * 4 + g] = acc;
    }
}

// ---------------------------------------------------------------------------
// Kernel 2: q~[m] = QSCALE * Wk^T (Wq pe_m + bq)  (fp16), cb[m] = QSCALE * q·bk
// ---------------------------------------------------------------------------
__global__ void k_qproj(const float* __restrict__ pe, const float* __restrict__ Wq,
                        const float* __restrict__ bq, const float* __restrict__ Wk,
                        const float* __restrict__ bk,
                        _Float16* __restrict__ qh, float* __restrict__ cb) {
    int m = blockIdx.x;
    int d = threadIdx.x;  // 0..127
    __shared__ float pe_s[PED];
    __shared__ float q_s[PED];
    __shared__ float red_s[2];
    pe_s[d] = pe[m * PED + d];
    __syncthreads();
    const float* wr = Wq + d * PED;
    float a = bq[d];
#pragma unroll 8
    for (int p = 0; p < PED; ++p) a = fmaf(pe_s[p], wr[p], a);
    q_s[d] = a;
    float pb = a * bk[d];
#pragma unroll
    for (int off = 32; off; off >>= 1) pb += __shfl_xor(pb, off, 64);
    if ((d & 63) == 0) red_s[d >> 6] = pb;
    __syncthreads();
    float acc = 0.f;
#pragma unroll 8
    for (int p = 0; p < PED; ++p) acc = fmaf(q_s[p], Wk[p * PED + d], acc);
    qh[m * PED + d] = (_Float16)(acc * QSCALE);
    if (d == 0) cb[m] = (red_s[0] + red_s[1]) * QSCALE;
}

// ---------------------------------------------------------------------------
// Kernel 3: LSTM scan via MFMA. 128 blocks x 512 threads (8 waves = 2/SIMD),
// 4 obs-rows/block, obs-row j stored at A-row 4j. Then C[row=4*quad][col=l15]
// puts exactly ONE cell per lane in acc[g][0]: no shuffles, no gate exchange.
// apre is folded into the MFMA accumulator init. Batched-rcp nonlinearities.
// ---------------------------------------------------------------------------
__global__ __launch_bounds__(512, 1)
void k_lstm(const float* __restrict__ xnorm, const float* __restrict__ apre_p,
            const float* __restrict__ W_ih, const float* __restrict__ W_hh,
            _Float16* __restrict__ H16) {
    const int tid = threadIdx.x;
    const int lane = tid & 63, wv = tid >> 6;     // 8 waves
    const int l15 = lane & 15, quad = lane >> 4;
    const int n0 = blockIdx.x * 4;
    const int p = 16 * wv + l15;                  // gate/h unit this lane owns

    // ---- stationary B-fragments: B[n=col][k] = W_hh[col][k], col = 128g+p
    half8 bfr[4][4];
    float wih0[4];
#pragma unroll
    for (int g = 0; g < 4; ++g) {
        const int col = 128 * g + p;
        const float* wrow = W_hh + (size_t)col * PED;
#pragma unroll
        for (int c = 0; c < 4; ++c) {
            const int k0 = c * 32 + quad * 8;
            float4 f0 = *(const float4*)(wrow + k0);
            float4 f1 = *(const float4*)(wrow + k0 + 4);
            bfr[g][c] = (half8){(_Float16)f0.x, (_Float16)f0.y, (_Float16)f0.z, (_Float16)f0.w,
                                (_Float16)f1.x, (_Float16)f1.y, (_Float16)f1.z, (_Float16)f1.w};
        }
        wih0[g] = W_ih[(size_t)col * 33];
    }

    __shared__ _Float16 h_s[2][16 * HSTR];        // A-rows 4j hold h, rest zero
    __shared__ float x_s[T_STEPS * 4];            // 4 KB

    for (int idx = tid; idx < T_STEPS * 4; idx += 512)
        x_s[idx] = xnorm[(idx >> 2) * OBS + n0 + (idx & 3)];
    for (int idx = tid; idx < 2 * 16 * HSTR; idx += 512)
        ((_Float16*)h_s)[idx] = (_Float16)0.f;

    float c0 = 0.f;
    const float* apl = apre_p + p * 4;
    float4 ap = *(const float4*)(apl);            // (gi,gf,gg,go) pre-adds for t=0
    __syncthreads();

    _Float16* Hg = H16 + (size_t)(n0 + quad) * MSG + p;
    int buf = 0;
    for (int t = 0; t < T_STEPS; ++t) {
        // ---- A-fragments: A[m=l15][k] from h_s (b128, conflict-free)
        half8 af[4];
        const _Float16* hb = h_s[buf] + l15 * HSTR + quad * 8;
#pragma unroll
        for (int c = 0; c < 4; ++c) af[c] = *(const half8*)(hb + c * 32);

        // ---- gates via MFMA, apre folded into acc init
        floatx4 acc[4];
        acc[0] = (floatx4){ap.x, ap.x, ap.x, ap.x};
        acc[1] = (floatx4){ap.y, ap.y, ap.y, ap.y};
        acc[2] = (floatx4){ap.z, ap.z, ap.z, ap.z};
        acc[3] = (floatx4){ap.w, ap.w, ap.w, ap.w};
#pragma unroll
        for (int g = 0; g < 4; ++g)
#pragma unroll
            for (int c = 0; c < 4; ++c)
                acc[g] = __builtin_amdgcn_mfma_f32_16x16x32_f16(
                    af[c], bfr[g][c], acc[g], 0, 0, 0);

        // ---- prefetch apre for t+1 (off critical path)
        const int tn = (t + 1 < T_STEPS) ? t + 1 : t;
        float4 ap_n = *(const float4*)(apl + tn * GATES);

        // ---- this lane's single cell: obs-row quad, unit p (C row 4*quad)
        const float x = x_s[t * 4 + quad];
        float gi = fmaf(x, wih0[0], acc[0][0]);
        float gf = fmaf(x, wih0[1], acc[1][0]);
        float gg = fmaf(x, wih0[2], acc[2][0]);
        float go = fmaf(x, wih0[3], acc[3][0]);

        // batched-rcp: 3 denominators, 1 rcp
        float Di = 1.f + fast_exp2(fminf(-L1 * gi, 20.f));
        float Df = 1.f + fast_exp2(fminf(-L1 * gf, 20.f));
        float Dg = 1.f + fast_exp2(fminf(L2C * gg, 20.f));
        float DfDg = Df * Dg, DiDg = Di * Dg, DiDf = Di * Df;
        float r3 = fast_rcp(Di * DfDg);
        float iDi = r3 * DfDg, iDf = r3 * DiDg, iDg = r3 * DiDf;
        float cn = fmaf(iDf, c0, iDi * fmaf(-2.f, iDg, 1.f));
        c0 = cn;
        float Do = 1.f + fast_exp2(fminf(-L1 * go, 20.f));
        float Dc = 1.f + fast_exp2(fminf(L2C * cn, 20.f));
        float r2 = fast_rcp(Do * Dc);
        float iDo = r2 * Dc, iDc = r2 * Do;
        _Float16 hq = (_Float16)(iDo * fmaf(-2.f, iDc, 1.f));

        // ---- write h to next LDS buffer (A-row 4*quad) + global H16
        h_s[buf ^ 1][(4 * quad) * HSTR + p] = hq;
        Hg[0] = hq;
        Hg += OBS * MSG;

        ap = ap_n;
        buf ^= 1;
        __syncthreads();
    }
}

// ---------------------------------------------------------------------------
// Kernel 4: attention via fp16 MFMA (LDS-staged, R7 structure) with XCD-aware
// swizzle: t = blockIdx & 255, mq = blockIdx >> 8, so all 8 blocks sharing a
// t have the same blockIdx%8 -> same XCD (round-robin dispatch) -> H16[t] is
// fetched into that XCD's L2 once and shared, instead of streaming the whole
// 33.5 MB H16 through every XCD's L2.
// ---------------------------------------------------------------------------
__global__ __launch_bounds__(256, 4)
void k_attn(const _Float16* __restrict__ qh, const float* __restrict__ cb,
            const _Float16* __restrict__ H16, const float* __restrict__ xnorm,
            float* __restrict__ outp) {
    const int t = blockIdx.x & 255;
    const int mq = blockIdx.x >> 8;               // 0..7
    const int tid = threadIdx.x;
    const int lane = tid & 63, wave = tid >> 6;
    const int l15 = lane & 15, quad = lane >> 4;
    const int m0 = mq * 128 + wave * 32;

    half8 afrag[2][4];
    floatx4 cbv[2];
#pragma unroll
    for (int mt = 0; mt < 2; ++mt) {
        const half8* qrow = (const half8*)(qh + (size_t)(m0 + mt * 16 + l15) * PED);
#pragma unroll
        for (int c = 0; c < 4; ++c) afrag[mt][c] = qrow[c * 4 + quad];
        cbv[mt] = *(const floatx4*)(cb + m0 + mt * 16 + quad * 4);
    }

    __shared__ half8 kbuf[64 * KSTR];   // 64 rows x 17 half8 (padded)
    __shared__ float s_s[64];

    float outacc[8];
#pragma unroll
    for (int i = 0; i < 8; ++i) outacc[i] = 0.f;

    const half8* Ht = (const half8*)(H16 + (size_t)t * (OBS * MSG));
    half8 pf[4];
    float sf = 0.f;
#pragma unroll
    for (int i = 0; i < 4; ++i) pf[i] = Ht[i * 256 + tid];
    if (tid < 64) sf = xnorm[t * OBS + tid];

    for (int ch = 0; ch < 8; ++ch) {
        __syncthreads();
#pragma unroll
        for (int i = 0; i < 4; ++i) {
            int f = i * 256 + tid;
            kbuf[(f >> 4) * KSTR + (f & 15)] = pf[i];
        }
        if (tid < 64) s_s[tid] = sf;
        __syncthreads();
        if (ch < 7) {
            const half8* Hn = Ht + (ch + 1) * 1024;
#pragma unroll
            for (int i = 0; i < 4; ++i) pf[i] = Hn[i * 256 + tid];
            if (tid < 64) sf = xnorm[t * OBS + (ch + 1) * 64 + tid];
        }

#pragma unroll
        for (int nt = 0; nt < 4; ++nt) {
            half8 bfrag[4];
#pragma unroll
            for (int c = 0; c < 4; ++c)
                bfrag[c] = kbuf[(nt * 16 + l15) * KSTR + c * 4 + quad];

            floatx4 acc[2];
#pragma unroll
            for (int mt = 0; mt < 2; ++mt) {
                acc[mt] = cbv[mt];
#pragma unroll
                for (int c = 0; c < 4; ++c)
                    acc[mt] = __builtin_amdgcn_mfma_f32_16x16x32_f16(
                        afrag[mt][c], bfrag[c], acc[mt], 0, 0, 0);
            }

            const float sv = s_s[nt * 16 + l15];
#pragma unroll
            for (int mt = 0; mt < 2; ++mt) {
                float E0 = fast_exp2(fminf(acc[mt][0], 20.f));
                float E1 = fast_exp2(fminf(acc[mt][1], 20.f));
                float E2 = fast_exp2(fminf(acc[mt][2], 20.f));
                float E3 = fast_exp2(fminf(acc[mt][3], 20.f));
                float D0 = 1.f + E0, D1 = 1.f + E1, D2 = 1.f + E2, D3 = 1.f + E3;
                float m01 = D0 * D1, m23 = D2 * D3;
                float rp = fast_rcp(m01 * m23);
                float rA = rp * m23, rB = rp * m01;
                float i0 = rA * D1, i1 = rA * D0, i2 = rB * D3, i3 = rB * D2;
                outacc[mt * 4 + 0] = fmaf(fmaf(-2.f, i0, 1.f), sv, outacc[mt * 4 + 0]);
                outacc[mt * 4 + 1] = fmaf(fmaf(-2.f, i1, 1.f), sv, outacc[mt * 4 + 1]);
                outacc[mt * 4 + 2] = fmaf(fmaf(-2.f, i2, 1.f), sv, outacc[mt * 4 + 2]);
                outacc[mt * 4 + 3] = fmaf(fmaf(-2.f, i3, 1.f), sv, outacc[mt * 4 + 3]);
            }
        }
    }

#pragma unroll
    for (int i = 0; i < 8; ++i) {
        float v = outacc[i];
        v += __shfl_xor(v, 1, 16);
        v += __shfl_xor(v, 2, 16);
        v += __shfl_xor(v, 4, 16);
        v += __shfl_xor(v, 8, 16);
        outacc[i] = v;
    }
    if (l15 == 0) {
        const int mbase = m0 + quad * 4;
#pragma unroll
        for (int mt = 0; mt < 2; ++mt)
#pragma unroll
            for (int r = 0; r < 4; ++r)
                outp[(size_t)t * HID + mbase + mt * 16 + r] = tanh_f(outacc[mt * 4 + r]);
    }
}

// ---------------------------------------------------------------------------
extern "C" void kernel_launch(void* const* d_in, const int* in_sizes, int n_in,
                              void* d_out, int out_size, void* d_ws, size_t ws_size,
                              hipStream_t stream) {
    const float* obs      = (const float*)d_in[0];   // (256,512)
    const float* prev_act = (const float*)d_in[1];   // (256,32)
    const float* in_shift = (const float*)d_in[2];   // (512,)
    const float* in_scale = (const float*)d_in[3];   // (512,)
    const float* pos_emb  = (const float*)d_in[4];   // (1024,128)
    const float* W_ih     = (const float*)d_in[5];   // (512,33)
    const float* b_ih     = (const float*)d_in[6];   // (512,)
    const float* W_hh     = (const float*)d_in[7];   // (512,128)
    const float* b_hh     = (const float*)d_in[8];   // (512,)
    const float* Wq       = (const float*)d_in[9];   // (128,128)
    const float* bq       = (const float*)d_in[10];  // (128,)
    const float* Wk       = (const float*)d_in[11];  // (128,128)
    const float* bk       = (const float*)d_in[12];  // (128,)
    float* outp = (float*)d_out;                     // (256,1024)

    // workspace layout (float offsets):
    //   xnorm:  0        (131072 f)
    //   apre_p: 131072   (131072 f)
    //   qh:     262144   (131072 halfs = 65536 f)
    //   cb:     327680   (1024 f)
    //   H16:    328704   (16777216 halfs)
    float* ws = (float*)d_ws;
    float* xnorm  = ws;
    float* apre_p = ws + 131072;
    _Float16* qh  = (_Float16*)(ws + 262144);
    float* cbuf   = ws + 327680;
    _Float16* H16 = (_Float16*)(ws + 328704);

    k_pre<<<T_STEPS, 256, 0, stream>>>(obs, prev_act, in_shift, in_scale,
                                       W_ih, b_ih, b_hh, xnorm, apre_p);
    k_qproj<<<HID, 128, 0, stream>>>(pos_emb, Wq, bq, Wk, bk, qh, cbuf);
    k_lstm<<<128, 512, 0, stream>>>(xnorm, apre_p, W_ih, W_hh, H16);
    k_attn<<<T_STEPS * 8, 256, 0, stream>>>(qh, cbuf, H16, xnorm, outp);
}